// Round 15
// baseline (19.307 us; speedup 1.0000x reference)
//
#include <hip/hip_runtime.h>
#include <math.h>

#define BB 2
#define LL 1024
#define DD 256
#define UU 32
#define RPB 4                   // rows per attn block
#define UNION (128 + RPB - 1)   // 131-row union band
#define KROW 36                 // padded LDS k row: b128-aligned, 2-way bank alias (free)
#define TPB 1024
#define NGRP 8                  // phase-3 jru groups
#define NROW (BB * LL)
// prescale so tanh(v) = 1 - 2*rcp(exp2(SC*v)+1), SC = 2*log2(e)
#define SCALE 2.88539008177793f

// ---------------- qk: 2 rows/block, 2 waves per row (16-way d-split) ----------------
// 1024 blocks x 256 thr -> 4 blocks/CU x 4 waves = 16 waves/CU (was 8).
// Emits Eq = exp2(SC*q), Ek = exp2(SC*(k+bh)).
__global__ __launch_bounds__(256) void qk_kernel(
    const float* __restrict__ x, const float* __restrict__ Wt,
    const float* __restrict__ Wx, const float* __restrict__ bh,
    float* __restrict__ q, float* __restrict__ k)
{
    __shared__ float s_red[2][2][8][8];   // [wave-half][r][u4][q0..3,k0..3]
    int t = threadIdx.x;
    int u4 = t & 7;             // 4 u-columns: u0 = u4*4
    int dh = (t >> 3) & 15;     // d-range sixteenth (16 d each)
    int r  = t >> 7;            // row within block (2 rows)
    int wh = dh >> 3;           // which wave-half of this row
    int row = blockIdx.x * 2 + r;
    int u0 = u4 * 4;
    const float* xr  = x  + (size_t)row * DD + dh * 16;
    const float* wtp = Wt + (size_t)(dh * 16) * UU + u0;
    const float* wxp = Wx + (size_t)(dh * 16) * UU + u0;
    float q0=0.f,q1=0.f,q2=0.f,q3=0.f, k0=0.f,k1=0.f,k2=0.f,k3=0.f;
    #pragma unroll
    for (int dd = 0; dd < 16; dd += 4) {
        float4 xv = *(const float4*)(xr + dd);
        float4 w;
        w = *(const float4*)(wtp + (dd + 0) * UU);
        q0=fmaf(xv.x,w.x,q0); q1=fmaf(xv.x,w.y,q1); q2=fmaf(xv.x,w.z,q2); q3=fmaf(xv.x,w.w,q3);
        w = *(const float4*)(wxp + (dd + 0) * UU);
        k0=fmaf(xv.x,w.x,k0); k1=fmaf(xv.x,w.y,k1); k2=fmaf(xv.x,w.z,k2); k3=fmaf(xv.x,w.w,k3);
        w = *(const float4*)(wtp + (dd + 1) * UU);
        q0=fmaf(xv.y,w.x,q0); q1=fmaf(xv.y,w.y,q1); q2=fmaf(xv.y,w.z,q2); q3=fmaf(xv.y,w.w,q3);
        w = *(const float4*)(wxp + (dd + 1) * UU);
        k0=fmaf(xv.y,w.x,k0); k1=fmaf(xv.y,w.y,k1); k2=fmaf(xv.y,w.z,k2); k3=fmaf(xv.y,w.w,k3);
        w = *(const float4*)(wtp + (dd + 2) * UU);
        q0=fmaf(xv.z,w.x,q0); q1=fmaf(xv.z,w.y,q1); q2=fmaf(xv.z,w.z,q2); q3=fmaf(xv.z,w.w,q3);
        w = *(const float4*)(wxp + (dd + 2) * UU);
        k0=fmaf(xv.z,w.x,k0); k1=fmaf(xv.z,w.y,k1); k2=fmaf(xv.z,w.z,k2); k3=fmaf(xv.z,w.w,k3);
        w = *(const float4*)(wtp + (dd + 3) * UU);
        q0=fmaf(xv.w,w.x,q0); q1=fmaf(xv.w,w.y,q1); q2=fmaf(xv.w,w.z,q2); q3=fmaf(xv.w,w.w,q3);
        w = *(const float4*)(wxp + (dd + 3) * UU);
        k0=fmaf(xv.w,w.x,k0); k1=fmaf(xv.w,w.y,k1); k2=fmaf(xv.w,w.z,k2); k3=fmaf(xv.w,w.w,k3);
    }
    // intra-wave reduce over dh&7 (lane bits 3-5)
    #pragma unroll
    for (int off = 8; off < 64; off <<= 1) {
        q0 += __shfl_xor(q0, off); q1 += __shfl_xor(q1, off);
        q2 += __shfl_xor(q2, off); q3 += __shfl_xor(q3, off);
        k0 += __shfl_xor(k0, off); k1 += __shfl_xor(k1, off);
        k2 += __shfl_xor(k2, off); k3 += __shfl_xor(k3, off);
    }
    if ((dh & 7) == 0) {
        float* p = &s_red[wh][r][u4][0];
        p[0]=q0; p[1]=q1; p[2]=q2; p[3]=q3;
        p[4]=k0; p[5]=k1; p[6]=k2; p[7]=k3;
    }
    __syncthreads();
    // final combine + exp2 + store: 2 rows x 32 u = 64 outputs, threads 0-63
    if (t < 64) {
        int rr = t >> 5, u = t & 31;
        int uu4 = u >> 2, c = u & 3;
        int orow = blockIdx.x * 2 + rr;
        float qv = s_red[0][rr][uu4][c]     + s_red[1][rr][uu4][c];
        float kv = s_red[0][rr][uu4][4 + c] + s_red[1][rr][uu4][4 + c];
        q[(size_t)orow * UU + u] = __builtin_amdgcn_exp2f(SCALE * qv);
        k[(size_t)orow * UU + u] = __builtin_amdgcn_exp2f(SCALE * (kv + bh[u]));
    }
}

// ---------------- attn (R14 verbatim): 4 rows per 1024-thread block, 512 blocks ----------------
__global__ __launch_bounds__(TPB, 8) void attn_kernel(
    const float* __restrict__ x, const float* __restrict__ qs,
    const float* __restrict__ ks, const float* __restrict__ Wa,
    const float* __restrict__ ba, float* __restrict__ out)
{
    __shared__ float s_k[UNION * KROW];         // Ek band (18.9 KB)
    __shared__ float s_a4[(UNION + 1) * RPB];   // e-values, [jru][r], 16B rows
    __shared__ float s_q[RPB * UU];             // Eq
    __shared__ float s_wa[UU];
    __shared__ float s_c0;                      // ba + sum(Wa)
    __shared__ float s_inv[RPB];
    __shared__ float s_part[NGRP * RPB * DD];   // phase-3 group partials (32 KB)

    int t = threadIdx.x;
    int blk = blockIdx.x;
    int i0L = (blk * RPB) & (LL - 1);
    int b   = (blk * RPB) >> 10;
    int rowbase = blk * RPB;
    int j0L = i0L - 64;                          // union band start (local, signed)

    // ---- staging (all LDS-fed phase 1) ----
    if (t < RPB * UU) s_q[t] = qs[(size_t)rowbase * UU + t];
    if (t >= 128 && t < 128 + UU) s_wa[t - 128] = Wa[t - 128];
    if (t == 160) {
        float sw = ba[0];
        #pragma unroll
        for (int u = 0; u < UU; ++u) sw += Wa[u];
        s_c0 = sw;
    }
    if (t < (UNION + 1) * RPB) s_a4[t] = 0.0f;
    for (int idx = t; idx < UNION * 8; idx += TPB) {
        int jru = idx >> 3, uq = idx & 7;
        int jl = j0L + jru;
        if ((unsigned)jl < (unsigned)LL) {
            float4 kv = *(const float4*)(ks + (size_t)(b * LL + jl) * UU + uq * 4);
            *(float4*)&s_k[jru * KROW + uq * 4] = kv;
        }
    }
    __syncthreads();

    // ---- Phase 1: 512 e-entries, 2 threads each (16 u/thread), all-LDS operands ----
    // tanh term: 1 - 2*rcp(Eq*Ek + 1)
    {
        int entry = t >> 1, half = t & 1;
        int r = entry >> 7, jr = entry & 127;    // r wave-uniform
        int jru = r + jr;
        int jl = j0L + jru;                      // band condition == jl in [0,LL)
        float acc = 0.0f;
        if ((unsigned)jl < (unsigned)LL) {
            const float* kp = &s_k[jru * KROW + half * 16];
            const float* qp = &s_q[r * UU + half * 16];
            const float* wp = &s_wa[half * 16];
            #pragma unroll
            for (int u = 0; u < 16; u += 4) {
                float4 k4 = *(const float4*)(kp + u);    // ds_read_b128, 2-way alias
                float4 q4 = *(const float4*)(qp + u);    // LDS broadcast
                float4 w4 = *(const float4*)(wp + u);    // LDS broadcast
                acc = fmaf(w4.x, __builtin_amdgcn_rcpf(fmaf(q4.x, k4.x, 1.0f)), acc);
                acc = fmaf(w4.y, __builtin_amdgcn_rcpf(fmaf(q4.y, k4.y, 1.0f)), acc);
                acc = fmaf(w4.z, __builtin_amdgcn_rcpf(fmaf(q4.z, k4.z, 1.0f)), acc);
                acc = fmaf(w4.w, __builtin_amdgcn_rcpf(fmaf(q4.w, k4.w, 1.0f)), acc);
            }
        }
        acc += __shfl_xor(acc, 1);               // pair shares same jl
        if (half == 0 && (unsigned)jl < (unsigned)LL)
            s_a4[jru * RPB + r] = __expf(fmaf(-2.0f, acc, s_c0));
    }
    __syncthreads();

    // ---- Phase 2 (waves 0-3): per-row denominators; s_inv read only after next barrier ----
    if (t < 4 * 64) {
        int r = t >> 6, lane = t & 63;
        float v = s_a4[lane * RPB + r] + s_a4[(lane + 64) * RPB + r];
        if (lane < UNION + 1 - 128) v += s_a4[(lane + 128) * RPB + r];
        #pragma unroll
        for (int off = 32; off > 0; off >>= 1) v += __shfl_xor(v, off);
        if (lane == 0) s_inv[r] = 1.0f / (v + 1e-7f);
    }

    // ---- Phase 3: thread (dq:64, rh:2, g:8); rh splits the d-range ----
    {
        int dq = t & 63, rh = (t >> 6) & 1, g = t >> 7;
        int d0 = rh * 128 + dq * 2;
        float p00 = 0.f, p01 = 0.f, p10 = 0.f, p11 = 0.f;
        float p20 = 0.f, p21 = 0.f, p30 = 0.f, p31 = 0.f;
        const float* xb = x + (size_t)b * LL * DD + d0;
        for (int jru = g; jru < UNION; jru += NGRP) {
            int jl = j0L + jru;                  // wave-uniform guard
            if ((unsigned)jl < (unsigned)LL) {
                float2 xv = *(const float2*)(xb + (size_t)jl * DD);
                float4 e4 = *(const float4*)&s_a4[jru * RPB];   // uniform b128 broadcast
                p00 = fmaf(e4.x, xv.x, p00); p01 = fmaf(e4.x, xv.y, p01);
                p10 = fmaf(e4.y, xv.x, p10); p11 = fmaf(e4.y, xv.y, p11);
                p20 = fmaf(e4.z, xv.x, p20); p21 = fmaf(e4.z, xv.y, p21);
                p30 = fmaf(e4.w, xv.x, p30); p31 = fmaf(e4.w, xv.y, p31);
            }
        }
        *(float2*)&s_part[(g * RPB + 0) * DD + d0] = make_float2(p00, p01);
        *(float2*)&s_part[(g * RPB + 1) * DD + d0] = make_float2(p10, p11);
        *(float2*)&s_part[(g * RPB + 2) * DD + d0] = make_float2(p20, p21);
        *(float2*)&s_part[(g * RPB + 3) * DD + d0] = make_float2(p30, p31);
    }
    __syncthreads();

    // ---- Epilogue: reduce 8 group partials, normalize, store ----
    {
        int r = t >> 8, d = t & 255;
        float v = 0.0f;
        #pragma unroll
        for (int g = 0; g < NGRP; ++g)
            v += s_part[(g * RPB + r) * DD + d];
        out[(size_t)(rowbase + r) * DD + d] = v * s_inv[r];
    }
}

extern "C" void kernel_launch(void* const* d_in, const int* in_sizes, int n_in,
                              void* d_out, int out_size, void* d_ws, size_t ws_size,
                              hipStream_t stream) {
    const float* x  = (const float*)d_in[0];
    const float* Wt = (const float*)d_in[1];
    const float* Wx = (const float*)d_in[2];
    const float* bh = (const float*)d_in[3];
    const float* Wa = (const float*)d_in[4];
    const float* ba = (const float*)d_in[5];
    float* out = (float*)d_out;

    float* qs = (float*)d_ws;                     // [2048][32] Eq = exp2(SC*q)
    float* ks = qs + (size_t)NROW * UU;           // [2048][32] Ek = exp2(SC*(k+bh))

    qk_kernel<<<NROW / 2, 256, 0, stream>>>(x, Wt, Wx, bh, qs, ks);
    attn_kernel<<<NROW / RPB, TPB, 0, stream>>>(x, qs, ks, Wa, ba, out);
}